// Round 11
// baseline (259.401 us; speedup 1.0000x reference)
//
#include <hip/hip_runtime.h>
#include <hip/hip_bf16.h>
#include <math.h>

#define B_DIM 8
#define C_DIM 32
#define N_DIM 4096
#define KHALF 2048
#define NCH (KHALF / 32)   // 64 chunks per wave

typedef short bf16x8 __attribute__((ext_vector_type(8)));   // 8 bf16 = 4 VGPRs
typedef float f32x4 __attribute__((ext_vector_type(4)));
typedef unsigned int uint4v __attribute__((ext_vector_type(4)));
typedef unsigned short ushort8 __attribute__((ext_vector_type(8)));

__device__ __forceinline__ ushort f2bf_rne(float f) {
  unsigned u = __float_as_uint(f);
  u += 0x7FFF + ((u >> 16) & 1);
  return (ushort)(u >> 16);
}

// Prep A: cadjs[b,n] = mean_c x[b,c,n] * log2(e)   (pre-scaled for exp2)
__global__ __launch_bounds__(256) void prep_cadj(const float* __restrict__ x,
                                                 float* __restrict__ cadjs) {
  int idx = blockIdx.x * 256 + threadIdx.x;   // 0 .. B*N-1
  int b = idx >> 12;
  int n = idx & (N_DIM - 1);
  const float* p = x + (size_t)b * C_DIM * N_DIM + n;
  float s = 0.f;
#pragma unroll
  for (int c = 0; c < C_DIM; ++c) s += p[(size_t)c * N_DIM];
  cadjs[idx] = s * (1.44269504f / C_DIM);
}

// Prep B: feabT tiled bf16: feabT[((b*128 + n/32)*32 + c)*32 + n%32]
__global__ __launch_bounds__(256) void prep_feab(const float* __restrict__ x,
                                                 ushort* __restrict__ feabT) {
  int idx = blockIdx.x * 256 + threadIdx.x;   // 0 .. 8*32*256-1
  int g = idx & 255;           // n-group of 16
  int c = (idx >> 8) & 31;
  int b = idx >> 13;
  int n0 = g * 16;
  const float* p = x + ((size_t)(b * C_DIM + c)) * N_DIM + n0;
  ushort* q = feabT + ((size_t)(b * (N_DIM / 32) + (n0 >> 5)) * C_DIM + c) * 32 + (n0 & 31);
  ushort8 v0, v1;
#pragma unroll
  for (int j = 0; j < 8; ++j) v0[j] = f2bf_rne(p[j]);
#pragma unroll
  for (int j = 0; j < 8; ++j) v1[j] = f2bf_rne(p[8 + j]);
  *(ushort8*)q = v0;
  *(ushort8*)(q + 8) = v1;
}

// Fused kernel: block = 16 waves (1024 thr) = 8 batches x 2 K-halves, 16 cols.
// Wave = ONE batch (acc = 8 VGPRs, total ~55 regs -> fits the 64-reg budget of
// 2 blocks/CU = 8 waves/SIMD). The 8 same-khalf waves read IDENTICAL adj
// addresses -> L1-shared, adj read once chip-wide. No LDS / barriers in the
// main loop; 16 KB LDS pair-reduce + para*relu epilogue.
__global__ __launch_bounds__(1024, 8) void gcn_fused(
    const ushort* __restrict__ feabT, const float* __restrict__ adj,
    const float* __restrict__ cadjs, const float* __restrict__ para,
    float* __restrict__ out) {
  __shared__ float red[B_DIM][512];   // 16 KB

  const int tid = threadIdx.x;
  const int lane = tid & 63;
  const int w = tid >> 6;           // 0..15
  const int b = w & 7;              // batch
  const int khalf = w >> 3;         // 0..1
  const int quad = lane >> 4;
  const int l15 = lane & 15;
  const int colgrp = blockIdx.x;    // 0..255
  const int col = colgrp * 16 + l15;
  const int ksbase = khalf * KHALF;

  const float cm = cadjs[b * N_DIM + col];
  const float* ckb = cadjs + (size_t)b * N_DIM;
  const ushort* fb = feabT + (size_t)b * (N_DIM / 32) * (C_DIM * 32);

  f32x4 acc0 = {0.f, 0.f, 0.f, 0.f};   // channels 0-15
  f32x4 acc1 = {0.f, 0.f, 0.f, 0.f};   // channels 16-31

#pragma unroll 2
  for (int ch = 0; ch < NCH; ++ch) {
    const int kb = ksbase + ch * 32;

    // adj fragment: same addresses across the 8 same-khalf waves -> L1 hit x7
    float a2[8];
#pragma unroll
    for (int j = 0; j < 8; ++j)
      a2[j] = 2.0f * adj[(size_t)(kb + quad * 8 + j) * N_DIM + col];

    float ckv[8];
    *(f32x4*)&ckv[0] = *(const f32x4*)(ckb + kb + quad * 8);
    *(f32x4*)&ckv[4] = *(const f32x4*)(ckb + kb + quad * 8 + 4);

    const ushort* tile = fb + (size_t)(kb >> 5) * (C_DIM * 32);
    const bf16x8 fa0 = *(const bf16x8*)(tile + l15 * 32 + quad * 8);
    const bf16x8 fa1 = *(const bf16x8*)(tile + (16 + l15) * 32 + quad * 8);

    // w = 2*adj / (1 + exp2(|ck' - cm'|)), inputs pre-scaled by log2(e)
    uint4v wfu;
#pragma unroll
    for (int p = 0; p < 4; ++p) {
      float d0 = ckv[2 * p] - cm;
      float e0 = __builtin_amdgcn_exp2f(fabsf(d0));
      float w0 = a2[2 * p] * __builtin_amdgcn_rcpf(1.0f + e0);
      float d1 = ckv[2 * p + 1] - cm;
      float e1 = __builtin_amdgcn_exp2f(fabsf(d1));
      float w1 = a2[2 * p + 1] * __builtin_amdgcn_rcpf(1.0f + e1);
      // truncating bf16x2 pack: bytes [w0.b2, w0.b3, w1.b2, w1.b3]
      wfu[p] = __builtin_amdgcn_perm(__float_as_uint(w1), __float_as_uint(w0),
                                     0x07060302u);
    }
    const bf16x8 wf = __builtin_bit_cast(bf16x8, wfu);

    acc0 = __builtin_amdgcn_mfma_f32_16x16x32_bf16(fa0, wf, acc0, 0, 0, 0);
    acc1 = __builtin_amdgcn_mfma_f32_16x16x32_bf16(fa1, wf, acc1, 0, 0, 0);
  }

  // epilogue: khalf-1 waves stash partials; khalf-0 waves combine + store
  __syncthreads();
  if (khalf == 1) {
#pragma unroll
    for (int r = 0; r < 4; ++r) {
      red[b][(quad * 4 + r) * 16 + l15] = acc0[r];
      red[b][(16 + quad * 4 + r) * 16 + l15] = acc1[r];
    }
  }
  __syncthreads();
  if (khalf == 0) {
#pragma unroll
    for (int r = 0; r < 4; ++r) {
      const int c0 = quad * 4 + r;
      const int c1 = c0 + 16;
      float s0 = acc0[r] + red[b][c0 * 16 + l15];
      float s1 = acc1[r] + red[b][c1 * 16 + l15];
      s0 *= para[(size_t)c0 * N_DIM + col];
      s1 *= para[(size_t)c1 * N_DIM + col];
      out[((size_t)(b * C_DIM + c0)) * N_DIM + col] = fmaxf(s0, 0.f);
      out[((size_t)(b * C_DIM + c1)) * N_DIM + col] = fmaxf(s1, 0.f);
    }
  }
}

extern "C" void kernel_launch(void* const* d_in, const int* in_sizes, int n_in,
                              void* d_out, int out_size, void* d_ws, size_t ws_size,
                              hipStream_t stream) {
  const float* x = (const float*)d_in[0];     // [8,32,64,64]
  const float* para = (const float*)d_in[1];  // [1,32,64,64]
  const float* adj = (const float*)d_in[2];   // [4096,4096]
  float* out = (float*)d_out;

  // ws: cadjs (128 KB) | feabT (2 MB)  -- total 2.25 MB
  float* cadjs = (float*)d_ws;
  ushort* feabT = (ushort*)((char*)d_ws + (size_t)B_DIM * N_DIM * 4);

  prep_cadj<<<dim3(B_DIM * N_DIM / 256), dim3(256), 0, stream>>>(x, cadjs);
  prep_feab<<<dim3(B_DIM * C_DIM * (N_DIM / 16) / 256), dim3(256), 0, stream>>>(x, feabT);
  gcn_fused<<<dim3(N_DIM / 16), dim3(1024), 0, stream>>>(feabT, adj, cadjs, para, out);
}

// Round 12
// 145.991 us; speedup vs baseline: 1.7768x; 1.7768x over previous
//
#include <hip/hip_runtime.h>
#include <hip/hip_bf16.h>
#include <math.h>

#define B_DIM 8
#define C_DIM 32
#define N_DIM 4096
#define KSPLIT 2
#define KSL (N_DIM / KSPLIT)   // 2048 k per block
#define NCH (KSL / 32)         // 64 chunks

typedef short bf16x8 __attribute__((ext_vector_type(8)));   // 8 bf16 = 4 VGPRs
typedef float f32x4 __attribute__((ext_vector_type(4)));
typedef unsigned int uint4v __attribute__((ext_vector_type(4)));
typedef unsigned short ushort8 __attribute__((ext_vector_type(8)));

__device__ __forceinline__ ushort f2bf_rne(float f) {
  unsigned u = __float_as_uint(f);
  u += 0x7FFF + ((u >> 16) & 1);
  return (ushort)(u >> 16);
}

// Prep A: cadjs[b,n] = mean_c x[b,c,n] * log2(e)   (pre-scaled for exp2)
__global__ __launch_bounds__(256) void prep_cadj(const float* __restrict__ x,
                                                 float* __restrict__ cadjs) {
  int idx = blockIdx.x * 256 + threadIdx.x;   // 0 .. B*N-1
  int b = idx >> 12;
  int n = idx & (N_DIM - 1);
  const float* p = x + (size_t)b * C_DIM * N_DIM + n;
  float s = 0.f;
#pragma unroll
  for (int c = 0; c < C_DIM; ++c) s += p[(size_t)c * N_DIM];
  cadjs[idx] = s * (1.44269504f / C_DIM);
}

// Prep B: feabT tiled bf16: feabT[((b*128 + n/32)*32 + c)*32 + n%32]
__global__ __launch_bounds__(256) void prep_feab(const float* __restrict__ x,
                                                 ushort* __restrict__ feabT) {
  int idx = blockIdx.x * 256 + threadIdx.x;   // 0 .. 8*32*256-1
  int g = idx & 255;           // n-group of 16
  int c = (idx >> 8) & 31;
  int b = idx >> 13;
  int n0 = g * 16;
  const float* p = x + ((size_t)(b * C_DIM + c)) * N_DIM + n0;
  ushort* q = feabT + ((size_t)(b * (N_DIM / 32) + (n0 >> 5)) * C_DIM + c) * 32 + (n0 & 31);
  ushort8 v0, v1;
#pragma unroll
  for (int j = 0; j < 8; ++j) v0[j] = f2bf_rne(p[j]);
#pragma unroll
  for (int j = 0; j < 8; ++j) v1[j] = f2bf_rne(p[8 + j]);
  *(ushort8*)q = v0;
  *(ushort8*)(q + 8) = v1;
}

// Stage 1: block = 8 waves (512 thr); wave = ONE batch; block owns 16 cols x
// K-half 2048 x all 8 batches. Per chunk the block cooperatively stages the
// 2 KB adj tile (1 float/thread, depth-2 register pipeline -> HBM latency
// covered by a full chunk) into LDS; all 8 waves consume it via ds_read.
// adj latency is thus carried by LDS + 2 VGPRs/thread, not 8x8 registers:
// fat-wave ILP at 4 waves/SIMD. adj read exactly once chip-wide.
__global__ __launch_bounds__(512, 4) void gcn_stage1(
    const ushort* __restrict__ feabT, const float* __restrict__ adj,
    const float* __restrict__ cadjs, float* __restrict__ part) {
  __shared__ float abuf[512];   // 2 KB: [row 0..31][col16 0..15], holds 2*adj

  const int tid = threadIdx.x;
  const int lane = tid & 63;
  const int b = tid >> 6;           // wave id = batch
  const int quad = lane >> 4;
  const int l15 = lane & 15;
  const int colgrp = blockIdx.x;    // 0..255
  const int kh = blockIdx.y;        // 0..1
  const int col = colgrp * 16 + l15;
  const int ksbase = kh * KSL;

  // staging address: thread tid covers (row tid>>4, col tid&15) of each tile
  const float* agp = adj + (size_t)(ksbase + (tid >> 4)) * N_DIM + colgrp * 16 + (tid & 15);

  const float cm = cadjs[b * N_DIM + col];
  const float* ckb = cadjs + (size_t)b * N_DIM + ksbase;
  const ushort* fb = feabT + ((size_t)b * (N_DIM / 32) + (ksbase >> 5)) * (C_DIM * 32);

  f32x4 acc0 = {0.f, 0.f, 0.f, 0.f};   // channels 0-15
  f32x4 acc1 = {0.f, 0.f, 0.f, 0.f};   // channels 16-31

  // depth-2 adj staging pipeline (a_nxt = tile ch+1, a_nx2 = tile ch+2)
  float a_nxt = agp[0];
  float a_nx2 = agp[(size_t)32 * N_DIM];
  abuf[tid] = 2.0f * a_nxt;   // tile 0 into LDS
  a_nxt = a_nx2;
  __syncthreads();

  for (int ch = 0; ch < NCH; ++ch) {
    // issue tile ch+2's staging load now (~2 chunks of distance to its use)
    if (ch + 2 < NCH) a_nx2 = agp[(size_t)(ch + 2) * 32 * N_DIM];

    // fea fragments + cadj k-values for this wave's batch
    const ushort* tile = fb + (size_t)ch * (C_DIM * 32);
    const bf16x8 fa0 = *(const bf16x8*)(tile + l15 * 32 + quad * 8);
    const bf16x8 fa1 = *(const bf16x8*)(tile + (16 + l15) * 32 + quad * 8);
    float ckv[8];
    *(f32x4*)&ckv[0] = *(const f32x4*)(ckb + ch * 32 + quad * 8);
    *(f32x4*)&ckv[4] = *(const f32x4*)(ckb + ch * 32 + quad * 8 + 4);

    // adj fragment from LDS (shared by all 8 batches)
    float a2[8];
#pragma unroll
    for (int j = 0; j < 8; ++j) a2[j] = abuf[(quad * 8 + j) * 16 + l15];

    // w = 2*adj / (1 + exp2(|ck' - cm'|)), inputs pre-scaled by log2(e)
    uint4v wfu;
#pragma unroll
    for (int p = 0; p < 4; ++p) {
      float d0 = ckv[2 * p] - cm;
      float e0 = __builtin_amdgcn_exp2f(fabsf(d0));
      float w0 = a2[2 * p] * __builtin_amdgcn_rcpf(1.0f + e0);
      float d1 = ckv[2 * p + 1] - cm;
      float e1 = __builtin_amdgcn_exp2f(fabsf(d1));
      float w1 = a2[2 * p + 1] * __builtin_amdgcn_rcpf(1.0f + e1);
      // truncating bf16x2 pack: bytes [w0.b2, w0.b3, w1.b2, w1.b3]
      wfu[p] = __builtin_amdgcn_perm(__float_as_uint(w1), __float_as_uint(w0),
                                     0x07060302u);
    }
    const bf16x8 wf = __builtin_bit_cast(bf16x8, wfu);

    acc0 = __builtin_amdgcn_mfma_f32_16x16x32_bf16(fa0, wf, acc0, 0, 0, 0);
    acc1 = __builtin_amdgcn_mfma_f32_16x16x32_bf16(fa1, wf, acc1, 0, 0, 0);

    __syncthreads();   // all waves done reading abuf for tile ch
    if (ch + 1 < NCH) {
      abuf[tid] = 2.0f * a_nxt;   // value loaded >=1 full chunk ago
      a_nxt = a_nx2;
    }
    __syncthreads();   // staged writes visible to all waves
  }

  // partials: part[kh][b][c][col]   (D layout: col=l15, row=quad*4+r)
  float* pp = part + ((size_t)(kh * B_DIM + b) * C_DIM) * N_DIM;
#pragma unroll
  for (int r = 0; r < 4; ++r) {
    const int c0 = quad * 4 + r;
    pp[(size_t)c0 * N_DIM + col] = acc0[r];
    pp[(size_t)(c0 + 16) * N_DIM + col] = acc1[r];
  }
}

// Epilogue: out = relu(para * (part[0] + part[1]))
__global__ __launch_bounds__(256) void epilogue_kernel(const float* __restrict__ part,
                                                       const float* __restrict__ para,
                                                       float* __restrict__ out) {
  const int t = blockIdx.x * 256 + threadIdx.x;    // float4 groups
  const int m4 = (t & 1023) * 4;
  const int bc = t >> 10;                          // b*32 + c
  const int c = bc & 31;
  const size_t base = (size_t)bc * N_DIM + m4;

  f32x4 s = {0.f, 0.f, 0.f, 0.f};
#pragma unroll
  for (int ks = 0; ks < KSPLIT; ++ks)
    s += *(const f32x4*)(part + (size_t)ks * (B_DIM * C_DIM * N_DIM) + base);

  const f32x4 p = *(const f32x4*)(para + (size_t)c * N_DIM + m4);
  f32x4 o;
#pragma unroll
  for (int i = 0; i < 4; ++i) o[i] = fmaxf(s[i] * p[i], 0.f);
  *(f32x4*)(out + base) = o;
}

extern "C" void kernel_launch(void* const* d_in, const int* in_sizes, int n_in,
                              void* d_out, int out_size, void* d_ws, size_t ws_size,
                              hipStream_t stream) {
  const float* x = (const float*)d_in[0];     // [8,32,64,64]
  const float* para = (const float*)d_in[1];  // [1,32,64,64]
  const float* adj = (const float*)d_in[2];   // [4096,4096]
  float* out = (float*)d_out;

  // ws: part (8 MB) | cadjs (128 KB) | feabT (2 MB)
  float* part = (float*)d_ws;
  float* cadjs = (float*)((char*)d_ws + (size_t)KSPLIT * B_DIM * C_DIM * N_DIM * 4);
  ushort* feabT = (ushort*)((char*)cadjs + (size_t)B_DIM * N_DIM * 4);

  prep_cadj<<<dim3(B_DIM * N_DIM / 256), dim3(256), 0, stream>>>(x, cadjs);
  prep_feab<<<dim3(B_DIM * C_DIM * (N_DIM / 16) / 256), dim3(256), 0, stream>>>(x, feabT);
  gcn_stage1<<<dim3(N_DIM / 16, KSPLIT), dim3(512), 0, stream>>>(feabT, adj, cadjs, part);
  epilogue_kernel<<<dim3(B_DIM * C_DIM * N_DIM / 4 / 256), dim3(256), 0, stream>>>(part, para, out);
}